// Round 17
// baseline (159.849 us; speedup 1.0000x reference)
//
#include <hip/hip_runtime.h>

// Problem constants (from reference)
#define BATCH 16384
#define CNUM  8
#define DIN   256
#define NH0   512
#define NH1   256

#define BT       64            // batch rows per block (fallback kernel)
#define BTM      128           // batch rows per block (main kernel)
#define NTMAIN   1024          // 16 waves
#define NTHREADS 512           // fallback

#define X_ELEMS  (BATCH * DIN)        // 4194304
#define W0_ELEMS (CNUM * NH0 * DIN)   // 1048576
#define W1_ELEMS (CNUM * NH1 * NH0)   // 1048576
#define WS_NEED  ((size_t)(X_ELEMS + W0_ELEMS + W1_ELEMS) * 2)  // 12.6 MB bf16

typedef __bf16 bf16x8 __attribute__((ext_vector_type(8)));
typedef __bf16 bf16x4 __attribute__((ext_vector_type(4)));
typedef float  f32x4  __attribute__((ext_vector_type(4)));
typedef float  f32x8  __attribute__((ext_vector_type(8)));

#define MFMA16(a, b, c) __builtin_amdgcn_mfma_f32_16x16x32_bf16((a), (b), (c), 0, 0, 0)

// Volatile global load: CANNOT be sunk/reordered vs the volatile waitcnts
// below -- forces the issue distance the compiler refuses to hold (r4/r6/r13
// all re-sank compiler-visible prefetch to distance-1, VGPR pinned at 64).
#define GLD8(dst, addr) asm volatile("global_load_dwordx4 %0, %1, off" : "=v"(dst) : "v"(addr))
#define WAITV(n) asm volatile("s_waitcnt vmcnt(" #n ")" ::: "memory")
#define SCHED0() __builtin_amdgcn_sched_barrier(0)

// ---------------------------------------------------------------------------
// Prep: fp32 -> bf16 for x, W0, W1 into ws.  786432 chunks x 8 elems.
// ---------------------------------------------------------------------------
__global__ __launch_bounds__(256)
void cvt_bf16(const float* __restrict__ x, const float* __restrict__ W0,
              const float* __restrict__ W1, __bf16* __restrict__ ws) {
    const int i = blockIdx.x * 256 + threadIdx.x;   // chunk of 8 elems
    const float* src;
    __bf16* dst;
    int off;
    if (i < X_ELEMS / 8)                 { src = x;  dst = ws;                        off = i * 8; }
    else if (i < (X_ELEMS + W0_ELEMS)/8) { src = W0; dst = ws + X_ELEMS;             off = (i - X_ELEMS/8) * 8; }
    else                                 { src = W1; dst = ws + X_ELEMS + W0_ELEMS;  off = (i - (X_ELEMS + W0_ELEMS)/8) * 8; }
    f32x8 v = *(const f32x8*)(src + off);
    bf16x8 r;
    #pragma unroll
    for (int j = 0; j < 8; ++j) r[j] = (__bf16)v[j];
    *(bf16x8*)(dst + off) = r;
}

// ---------------------------------------------------------------------------
// Main fused kernel: BT=128, 16 waves, 4 barriers/block.
// grid = (BATCH/BTM)*CNUM = 1024; c = blockIdx&7 (XCD round-robin).
//
// r10 (94.4 us) + ASM-VOLATILE DEPTH-3 A-STREAM PIPELINES (only change).
// FIFO discipline (hand-traced, issue order == consumption order):
//   L0: prologue pairs 0,1,2 (6 loads). Step ks: wait pair ks
//       [ks<6: vmcnt(4) | ks==6: vmcnt(2) | ks==7: vmcnt(0)], sched_barrier,
//       MFMA cluster, refill pair ks+3 if ks<5.
//   L1: prologue loads 0,1,2 issued after barrier-2 (ride through epilogue).
//       Step ks: wait load ks [ks<14: vmcnt(2) | 14: vmcnt(1) | 15: vmcnt(0)],
//       sched_barrier, MFMA cluster, refill load ks+3 if ks<13.
// Compiler loads mixing with ours only OVER-wait (vmcnt waits on total
// outstanding; extras raise the retire requirement) -- correctness-safe.
//
// LDS: h0s = 128 granules x 1 KB (frag-major: granule = 16 m-rows x 32 k;
// lane l's 16 B = row l&15, k-slot l>>4 -> every ds_read_b128 is
// lane-contiguous, conflict-free). h0 granule g = bt*16 + (n>>5).
// xs (x tile, 64 granules, p = mt*8 + kc) aliases granules 0..63 in L0.
// ---------------------------------------------------------------------------
__global__ __launch_bounds__(NTMAIN, 4)
void confounder_main(const __bf16* __restrict__ ws,
                     const float* __restrict__ b0,
                     const float* __restrict__ b1,
                     const float* __restrict__ W2,
                     const float* __restrict__ b2,
                     float* __restrict__ out) {
    __shared__ __align__(16) __bf16 h0s[BTM * NH0];  // 131072 B
    __shared__ float red[16][BTM];                   // 8192 B
    __bf16* xs = h0s;                                // granules 0..63 alias

    const __bf16* xbf = ws;
    const __bf16* w0b = ws + X_ELEMS;
    const __bf16* w1b = ws + X_ELEMS + W0_ELEMS;

    const int c    = blockIdx.x & 7;
    const int mb   = blockIdx.x >> 3;
    const int row0 = mb * BTM;

    const int tid  = threadIdx.x;
    const int w    = tid >> 6;    // wave 0..15
    const int lane = tid & 63;
    const int l15  = lane & 15;
    const int l4   = lane >> 4;   // 0..3

    // ---- stage x tile (128 m x 256 k) into granules 0..63, frag-major -----
    #pragma unroll
    for (int q = 0; q < 4; ++q) {
        const int p  = w * 4 + q;             // 0..63
        const int mt = p >> 3, kc = p & 7;
        bf16x8 v = *(const bf16x8*)(xbf + (size_t)(row0 + mt * 16 + l15) * DIN + kc * 32 + 8 * l4);
        *(bf16x8*)(xs + (p * 64 + lane) * 8) = v;
    }

    // W0 rows: wave w covers n = w*32 + at*16 + l15 (at 0..1)
    const __bf16* w0r = w0b + ((size_t)c * NH0 + w * 32 + l15) * DIN + 8 * l4;
    // W1 rows: wave w covers o = w*16 + l15
    const __bf16* w1r = w1b + ((size_t)c * NH1 + w * 16 + l15) * NH0 + 8 * l4;

    // ---- L0 asm prologue: pairs 0,1,2 (cannot be sunk) --------------------
    bf16x8 A0[3], A1[3];
    GLD8(A0[0], w0r);
    GLD8(A1[0], w0r + 16 * DIN);
    GLD8(A0[1], w0r + 32);
    GLD8(A1[1], w0r + 16 * DIN + 32);
    GLD8(A0[2], w0r + 64);
    GLD8(A1[2], w0r + 16 * DIN + 64);
    __syncthreads();                                   // [barrier 1] xs ready

    // ================= Layer 0: n-slice 32, m = 128, K = 256 ===============
    f32x4 acc0[2][8];   // [at][bt] = 64 accumulation regs
    #pragma unroll
    for (int at = 0; at < 2; ++at)
        #pragma unroll
        for (int bt = 0; bt < 8; ++bt)
            acc0[at][bt] = (f32x4){0.f, 0.f, 0.f, 0.f};

    #pragma unroll
    for (int ks = 0; ks < 8; ++ks) {
        // wait for pair ks (outstanding: pairs ks..min(ks+2,7))
        if (ks < 6)      { WAITV(4); }
        else if (ks == 6){ WAITV(2); }
        else             { WAITV(0); }
        SCHED0();   // rule #18: stop MFMA hoist above the wait
        __builtin_amdgcn_s_setprio(1);
        #pragma unroll
        for (int bt = 0; bt < 8; ++bt) {
            bf16x8 bx = *(const bf16x8*)(xs + ((bt * 8 + ks) * 64 + lane) * 8);
            acc0[0][bt] = MFMA16(A0[ks % 3], bx, acc0[0][bt]);
            acc0[1][bt] = MFMA16(A1[ks % 3], bx, acc0[1][bt]);
        }
        __builtin_amdgcn_s_setprio(0);
        if (ks < 5) {   // refill slot just consumed with pair ks+3
            GLD8(A0[ks % 3], w0r + (ks + 3) * 32);
            GLD8(A1[ks % 3], w0r + 16 * DIN + (ks + 3) * 32);
        }
    }

    __syncthreads();                                   // [barrier 2] xs reads done

    // ---- L1 asm prologue: loads 0,1,2 (ride through the epilogue) ---------
    bf16x8 B[3];
    GLD8(B[0], w1r);
    GLD8(B[1], w1r + 32);
    GLD8(B[2], w1r + 64);

    // ---- epilogue: bias+relu+cvt -> h0 granule g = bt*16 + w --------------
    // n = w*32 + at*16 + 4*l4 + r, m = bt*16 + l15
    #pragma unroll
    for (int at = 0; at < 2; ++at) {
        const int nb = w * 32 + at * 16 + 4 * l4;
        const f32x4 b4 = *(const f32x4*)(b0 + c * NH0 + nb);
        const int sub = (at * 2 + (l4 >> 1)) * 128 + l15 * 8 + 4 * (l4 & 1);
        #pragma unroll
        for (int bt = 0; bt < 8; ++bt) {
            const int g = bt * 16 + w;
            bf16x4 pk;
            #pragma unroll
            for (int r = 0; r < 4; ++r) {
                float v = acc0[at][bt][r] + b4[r];
                v = v > 0.f ? v : 0.f;
                pk[r] = (__bf16)v;
            }
            *(bf16x4*)(&h0s[g * 512 + sub]) = pk;
        }
    }
    __syncthreads();                                   // [barrier 3] h0 complete

    // ================= Layer 1: o-slice 16, m = 128, K = 512 ===============
    // h0 granule for (ks, bt): g = bt*16 + ks
    f32x4 acc1[8];   // [bt] = 32 accumulation regs
    #pragma unroll
    for (int bt = 0; bt < 8; ++bt)
        acc1[bt] = (f32x4){0.f, 0.f, 0.f, 0.f};

    #pragma unroll
    for (int ks = 0; ks < 16; ++ks) {
        // wait for load ks (outstanding: loads ks..min(ks+2,15))
        if (ks < 14)      { WAITV(2); }
        else if (ks == 14){ WAITV(1); }
        else              { WAITV(0); }
        SCHED0();
        __builtin_amdgcn_s_setprio(1);
        #pragma unroll
        for (int bt = 0; bt < 8; ++bt) {
            bf16x8 bh = *(const bf16x8*)(&h0s[((bt * 16 + ks) * 64 + lane) * 8]);
            acc1[bt] = MFMA16(B[ks % 3], bh, acc1[bt]);
        }
        __builtin_amdgcn_s_setprio(0);
        if (ks < 13)
            GLD8(B[ks % 3], w1r + (ks + 3) * 32);
    }

    // ================= Layer 2 =============================================
    // acc1[bt]: o = w*16 + 4*l4 + r, m = bt*16 + l15
    float part[8] = {0.f, 0.f, 0.f, 0.f, 0.f, 0.f, 0.f, 0.f};
    {
        const int ob = w * 16 + 4 * l4;
        const f32x4 b1v = *(const f32x4*)(b1 + c * NH1 + ob);
        const f32x4 w2v = *(const f32x4*)(W2 + c * NH1 + ob);
        #pragma unroll
        for (int r = 0; r < 4; ++r) {
            #pragma unroll
            for (int bt = 0; bt < 8; ++bt) {
                float v = acc1[bt][r] + b1v[r];
                v = v > 0.f ? v : 0.f;
                part[bt] += v * w2v[r];
            }
        }
    }
    #pragma unroll
    for (int bt = 0; bt < 8; ++bt) {
        part[bt] += __shfl_xor(part[bt], 16, 64);
        part[bt] += __shfl_xor(part[bt], 32, 64);
    }
    if (l4 == 0) {
        #pragma unroll
        for (int bt = 0; bt < 8; ++bt)
            red[w][bt * 16 + l15] = part[bt];
    }
    __syncthreads();                                   // [barrier 4]

    if (tid < BTM) {
        float s = 0.f;
        #pragma unroll
        for (int ww = 0; ww < 16; ++ww) s += red[ww][tid];
        s += b2[c];
        out[(size_t)(row0 + tid) * CNUM + c] = s;
    }
}

// ---------------------------------------------------------------------------
// Fallback (fp32 loads, no workspace) in case ws_size < WS_NEED. BT=64 geom.
// ---------------------------------------------------------------------------
__device__ __forceinline__ bf16x8 ld_cvt8(const float* __restrict__ p) {
    f32x8 v = *(const f32x8*)p;
    bf16x8 r;
    #pragma unroll
    for (int i = 0; i < 8; ++i) r[i] = (__bf16)v[i];
    return r;
}

#define P0 (NH0 + 8)

__global__ __launch_bounds__(NTHREADS, 4)
void confounder_fused(const float* __restrict__ x,
                      const float* __restrict__ W0,
                      const float* __restrict__ b0,
                      const float* __restrict__ W1,
                      const float* __restrict__ b1,
                      const float* __restrict__ W2,
                      const float* __restrict__ b2,
                      float* __restrict__ out) {
    __shared__ __align__(16) __bf16 h0s[BT * P0];
    __shared__ float red[8][BT];

    const int c    = blockIdx.x & 7;
    const int mb   = blockIdx.x >> 3;
    const int row0 = mb * BT;
    const int tid  = threadIdx.x;
    const int w    = tid >> 6;
    const int lane = tid & 63;
    const int l15  = lane & 15;
    const int l4   = lane >> 4;

    f32x4 acc0[4][4];
    #pragma unroll
    for (int mt = 0; mt < 4; ++mt)
        #pragma unroll
        for (int nt = 0; nt < 4; ++nt)
            acc0[mt][nt] = (f32x4){0.f, 0.f, 0.f, 0.f};

    const float* xb  = x  + (size_t)(row0 + l15) * DIN + 8 * l4;
    const float* w0b = W0 + ((size_t)c * NH0 + w * 64 + l15) * DIN + 8 * l4;

    #pragma unroll
    for (int ks = 0; ks < DIN / 32; ++ks) {
        bf16x8 a[4];
        #pragma unroll
        for (int mt = 0; mt < 4; ++mt)
            a[mt] = ld_cvt8(xb + mt * 16 * DIN + ks * 32);
        #pragma unroll
        for (int nt = 0; nt < 4; ++nt) {
            bf16x8 bf = ld_cvt8(w0b + nt * 16 * DIN + ks * 32);
            #pragma unroll
            for (int mt = 0; mt < 4; ++mt)
                acc0[mt][nt] = __builtin_amdgcn_mfma_f32_16x16x32_bf16(a[mt], bf, acc0[mt][nt], 0, 0, 0);
        }
    }
    #pragma unroll
    for (int nt = 0; nt < 4; ++nt) {
        const int n    = (w * 4 + nt) * 16 + l15;
        const float bv = b0[c * NH0 + n];
        #pragma unroll
        for (int mt = 0; mt < 4; ++mt)
            #pragma unroll
            for (int r = 0; r < 4; ++r) {
                float v = acc0[mt][nt][r] + bv;
                v = v > 0.f ? v : 0.f;
                h0s[(mt * 16 + l4 * 4 + r) * P0 + n] = (__bf16)v;
            }
    }
    __syncthreads();

    f32x4 acc1[2][4];
    #pragma unroll
    for (int ot = 0; ot < 2; ++ot)
        #pragma unroll
        for (int nt = 0; nt < 4; ++nt)
            acc1[ot][nt] = (f32x4){0.f, 0.f, 0.f, 0.f};

    const float* w1b = W1 + ((size_t)c * NH1 + w * 32 + l15) * NH0 + 8 * l4;

    #pragma unroll
    for (int ks = 0; ks < NH0 / 32; ++ks) {
        bf16x8 a[2];
        #pragma unroll
        for (int ot = 0; ot < 2; ++ot)
            a[ot] = ld_cvt8(w1b + ot * 16 * NH0 + ks * 32);
        #pragma unroll
        for (int nt = 0; nt < 4; ++nt) {
            bf16x8 bf = *(const bf16x8*)(&h0s[(nt * 16 + l15) * P0 + ks * 32 + 8 * l4]);
            #pragma unroll
            for (int ot = 0; ot < 2; ++ot)
                acc1[ot][nt] = __builtin_amdgcn_mfma_f32_16x16x32_bf16(a[ot], bf, acc1[ot][nt], 0, 0, 0);
        }
    }

    float part[4] = {0.f, 0.f, 0.f, 0.f};
    #pragma unroll
    for (int ot = 0; ot < 2; ++ot)
        #pragma unroll
        for (int r = 0; r < 4; ++r) {
            const int o     = (2 * w + ot) * 16 + l4 * 4 + r;
            const float b1v = b1[c * NH1 + o];
            const float w2v = W2[c * NH1 + o];
            #pragma unroll
            for (int nt = 0; nt < 4; ++nt) {
                float v = acc1[ot][nt][r] + b1v;
                v = v > 0.f ? v : 0.f;
                part[nt] += v * w2v;
            }
        }
    #pragma unroll
    for (int nt = 0; nt < 4; ++nt) {
        part[nt] += __shfl_xor(part[nt], 16, 64);
        part[nt] += __shfl_xor(part[nt], 32, 64);
    }
    if (l4 == 0) {
        #pragma unroll
        for (int nt = 0; nt < 4; ++nt)
            red[w][nt * 16 + l15] = part[nt];
    }
    __syncthreads();

    if (tid < BT) {
        float s = 0.f;
        #pragma unroll
        for (int ww = 0; ww < 8; ++ww) s += red[ww][tid];
        s += b2[c];
        out[(size_t)(row0 + tid) * CNUM + c] = s;
    }
}

extern "C" void kernel_launch(void* const* d_in, const int* in_sizes, int n_in,
                              void* d_out, int out_size, void* d_ws, size_t ws_size,
                              hipStream_t stream) {
    const float* x  = (const float*)d_in[0];
    const float* W0 = (const float*)d_in[1];
    const float* b0 = (const float*)d_in[2];
    const float* W1 = (const float*)d_in[3];
    const float* b1 = (const float*)d_in[4];
    const float* W2 = (const float*)d_in[5];
    const float* b2 = (const float*)d_in[6];
    float* out = (float*)d_out;

    if (ws_size >= WS_NEED) {
        __bf16* ws = (__bf16*)d_ws;
        cvt_bf16<<<dim3((X_ELEMS + W0_ELEMS + W1_ELEMS) / 8 / 256), dim3(256), 0, stream>>>(x, W0, W1, ws);
        confounder_main<<<dim3((BATCH / BTM) * CNUM), dim3(NTMAIN), 0, stream>>>(ws, b0, b1, W2, b2, out);
    } else {
        confounder_fused<<<dim3((BATCH / BT) * CNUM), dim3(NTHREADS), 0, stream>>>(x, W0, b0, W1, b1, W2, b2, out);
    }
}